// Round 7
// baseline (1109.533 us; speedup 1.0000x reference)
//
#include <hip/hip_runtime.h>
#include <hip/hip_bf16.h>
#include <cstdint>
#include <cstddef>

#define N_NODES 50000
#define N_EDGES 800000
#define NSEL    4096
#define F       96     // H*HN == H*HE
#define K_ODF   16

typedef __attribute__((ext_vector_type(8))) short  short8;
typedef __attribute__((ext_vector_type(4))) float  floatx4;

using bf16 = __hip_bfloat16;

__device__ inline float b2f(bf16 x){ return __bfloat162float(x); }
__device__ inline bf16  f2b(float x){ return __float2bfloat16(x); }
__device__ inline short f2bs(float x){ return __builtin_bit_cast(short, __float2bfloat16(x)); }
__device__ inline int clampi(int v, int hi){ return v < 0 ? 0 : (v >= hi ? hi-1 : v); }

// monotone float<->unsigned key for atomicMax (sentinel 0 < every real key)
__device__ inline unsigned fkey(float f){
  unsigned b = __builtin_bit_cast(unsigned, f);
  return (b & 0x80000000u) ? ~b : (b | 0x80000000u);
}
__device__ inline float funkey(unsigned k){
  unsigned b = (k & 0x80000000u) ? (k & 0x7fffffffu) : ~k;
  return __builtin_bit_cast(float, b);
}

// packed bf16 add: (a.lo+b.lo, a.hi+b.hi) with RNE via f32
__device__ inline unsigned int addpk_bf16(unsigned int a, unsigned int b){
  float alo = __builtin_bit_cast(float, a<<16);
  float ahi = __builtin_bit_cast(float, a & 0xffff0000u);
  float blo = __builtin_bit_cast(float, b<<16);
  float bhi = __builtin_bit_cast(float, b & 0xffff0000u);
  unsigned int pl = (unsigned int)(unsigned short)f2bs(alo+blo);
  unsigned int ph = (unsigned int)(unsigned short)f2bs(ahi+bhi);
  return pl | (ph<<16);
}

// ---------------- storage policies ----------------
struct F32S {
  using T = float;
  static constexpr size_t bytes = 4;
  static __device__ short8 ld8(const T* p){
    float4 u = *(const float4*)p;
    float4 v = *(const float4*)(p+4);
    short8 r;
    r[0]=f2bs(u.x); r[1]=f2bs(u.y); r[2]=f2bs(u.z); r[3]=f2bs(u.w);
    r[4]=f2bs(v.x); r[5]=f2bs(v.y); r[6]=f2bs(v.z); r[7]=f2bs(v.w);
    return r;
  }
  static __device__ short8 lds_ld(const char*){ return short8{0,0,0,0,0,0,0,0}; }
  static __device__ void lds_st(char*, float){}
};
struct BF16S {
  using T = bf16;
  static constexpr size_t bytes = 2;
  static __device__ short8 ld8(const T* p){ return *(const short8*)p; }
  static __device__ short8 lds_ld(const char* p){ return *(const short8*)p; }
  static __device__ void lds_st(char* p, float v){ *(bf16*)p = f2b(v); }
};
struct FP8S {
  using T = unsigned char;
  static constexpr size_t bytes = 1;
  static __device__ short8 cvt8(int2 w){
    short8 r;
    r[0]=f2bs(__builtin_amdgcn_cvt_f32_fp8(w.x,0));
    r[1]=f2bs(__builtin_amdgcn_cvt_f32_fp8(w.x,1));
    r[2]=f2bs(__builtin_amdgcn_cvt_f32_fp8(w.x,2));
    r[3]=f2bs(__builtin_amdgcn_cvt_f32_fp8(w.x,3));
    r[4]=f2bs(__builtin_amdgcn_cvt_f32_fp8(w.y,0));
    r[5]=f2bs(__builtin_amdgcn_cvt_f32_fp8(w.y,1));
    r[6]=f2bs(__builtin_amdgcn_cvt_f32_fp8(w.y,2));
    r[7]=f2bs(__builtin_amdgcn_cvt_f32_fp8(w.y,3));
    return r;
  }
  static __device__ short8 ld8(const T* p){ return cvt8(*(const int2*)p); }
  static __device__ short8 lds_ld(const char* p){ return cvt8(*(const int2*)p); }
  static __device__ void lds_st(char* p, float v){
    int pk = __builtin_amdgcn_cvt_pk_fp8_f32(v, 0.f, 0, false);
    *(unsigned char*)p = (unsigned char)(pk & 0xff);
  }
};

// ---------------- weight prep: bf16 transposed Wt[c][k] ----------------
struct WP { const float* p[12]; };
#define WT_ELEMS (11*9216 + 1536)

__global__ void k_prep(WP w, bf16* __restrict__ Wt){
  int g = blockIdx.x*blockDim.x + threadIdx.x;
  if (g >= WT_ELEMS) return;
  float v;
  if (g < 11*9216){
    int id = g / 9216, s = g % 9216;
    int c = s / 96, k = s % 96;
    v = w.p[id][k*96 + c];
  } else {
    int s = g - 11*9216;
    int c = s / 16, k = s % 16;
    v = w.p[11][k*96 + c];
  }
  Wt[g] = f2b(v);
}

// ---------------- CSR build ----------------
__global__ void k_count(const int* __restrict__ dst, int* __restrict__ counts){
  int e = blockIdx.x*blockDim.x + threadIdx.x;
  if (e < N_EDGES) atomicAdd(&counts[clampi(dst[e], N_NODES)], 1);
}

__global__ void k_scan(const int* __restrict__ counts, int* __restrict__ row_ptr){
  const int T = 1024;
  const int n = N_NODES;
  int tid = threadIdx.x;
  int seg = (n + T - 1)/T;
  int start = tid*seg;
  int end = (start+seg < n) ? start+seg : n;
  int s = 0;
  for (int i=start;i<end;i++) s += counts[i];
  __shared__ int wsums[16];
  int lane = tid & 63, wid = tid >> 6;
  int v = s;
  #pragma unroll
  for (int off=1; off<64; off<<=1){
    int t = __shfl_up(v, off);
    if (lane >= off) v += t;
  }
  if (lane==63) wsums[wid] = v;
  __syncthreads();
  if (wid==0 && lane < 16){
    int w = wsums[lane];
    #pragma unroll
    for (int off=1; off<16; off<<=1){
      int t = __shfl_up(w, off);
      if (lane>=off) w += t;
    }
    wsums[lane] = w;
  }
  __syncthreads();
  int base = (wid>0 ? wsums[wid-1] : 0) + (v - s);
  int run = base;
  for (int i=start;i<end;i++){ row_ptr[i] = run; run += counts[i]; }
  if (tid==T-1) row_ptr[n] = run;
}

__global__ void k_fill(const int* __restrict__ dst, const int* __restrict__ row_ptr,
                       int* __restrict__ cursor, int* __restrict__ csr_e){
  int e = blockIdx.x*blockDim.x + threadIdx.x;
  if (e < N_EDGES){
    int t = clampi(dst[e], N_NODES);
    int pos = atomicAdd(&cursor[t], 1);
    int idx = row_ptr[t] + pos;
    if (idx >= 0 && idx < N_EDGES) csr_e[idx] = e;
  }
}

// ---------------- max-table init: 12 B per nf row (bytes 180..192) to sentinel 0 ----------------
__global__ void k_maxinit(unsigned* nfm){
  int t = blockIdx.x*blockDim.x + threadIdx.x;
  if (t < N_NODES*3){
    int n = t/3, h = t - n*3;
    *(unsigned*)((char*)nfm + (size_t)n*192 + 180 + h*4) = 0u;
  }
}

// ---------------- node GEMM: O = A @ W  (W from transposed bf16 Wt) ----------------
template<class AS>
__global__ __launch_bounds__(256) void k_node_gemm(
    const typename AS::T* A,
    const bf16* __restrict__ Wt_ni, const bf16* __restrict__ Wt_nj, const bf16* __restrict__ Wt_ns,
    bf16* __restrict__ NI, bf16* __restrict__ NJ, bf16* __restrict__ HS)
{
  const bf16* Wt; bf16* O;
  if (blockIdx.z==0){ Wt=Wt_ni; O=NI; } else if (blockIdx.z==1){ Wt=Wt_nj; O=NJ; } else { Wt=Wt_ns; O=HS; }
  int wave = threadIdx.x >> 6, lane = threadIdx.x & 63;
  int lo = lane & 15, q = lane >> 4;
  int m0 = (blockIdx.x*4 + wave)*16;
  int n0 = blockIdx.y*16;
  int row = m0 + lo; if (row >= N_NODES) row = N_NODES-1;
  floatx4 acc = {0.f,0.f,0.f,0.f};
  #pragma unroll
  for (int kb=0; kb<3; kb++){
    int k0 = kb*32 + q*8;
    short8 a = AS::ld8(A + (size_t)row*F + k0);
    short8 b = *(const short8*)(Wt + (size_t)(n0+lo)*96 + k0);
    acc = __builtin_amdgcn_mfma_f32_16x16x32_bf16(a,b,acc,0,0,0);
  }
  #pragma unroll
  for (int r=0;r<4;r++){
    int m = m0 + q*4 + r;
    if (m < N_NODES) O[(size_t)m*F + n0+lo] = f2b(acc[r]);
  }
}

// ---------------- fused edge kernel v5: CSR-sorted positions ----------------
// position p -> edge perm[p]. ef/logits stored at positions (linear).
// layer0 input EF is odfeat in ORIGINAL edge order (gathered via perm).
template<int K_IN, bool STORE_EF, class INS, class OUTS>
__global__ __launch_bounds__(256) void k_edge5(
    const typename INS::T* EF, const bf16* __restrict__ Wt,
    const bf16* __restrict__ NI, const bf16* __restrict__ NJ,
    const float* __restrict__ bias, const float* __restrict__ attn,
    const int* __restrict__ src, const int* __restrict__ dst,
    const int* __restrict__ perm,
    typename OUTS::T* EFO, float* __restrict__ logits, unsigned* nfmax)
{
  __shared__ __align__(16) char lds_ef[4][3328];
  __shared__ __align__(16) char lds_g[4][3328];
  __shared__ __align__(16) float lstage[4][48];

  int wave = threadIdx.x >> 6, lane = threadIdx.x & 63;
  int lo = lane & 15, q = lane >> 4;
  size_t p0 = ((size_t)blockIdx.x*4 + wave)*16;
  char* myl = lds_ef[wave];
  char* gl  = lds_g[wave];

  // ---- stage G = NI[src]+NJ[dst] (bf16); dst sorted -> NJ rows L1-local
  int eL[3], seL[3], deL[3];
  #pragma unroll
  for (int j=0;j<3;j++) eL[j] = perm[p0 + (j*64+lane)/12];
  #pragma unroll
  for (int j=0;j<3;j++){ seL[j] = clampi(src[eL[j]], N_NODES); deL[j] = clampi(dst[eL[j]], N_NODES); }
  #pragma unroll
  for (int j=0;j<3;j++){
    int chunk = j*64 + lane;
    int er = chunk/12, c16 = chunk - er*12;
    uint4 a = *(const uint4*)((const char*)NI + (size_t)seL[j]*192 + c16*16);
    uint4 b = *(const uint4*)((const char*)NJ + (size_t)deL[j]*192 + c16*16);
    uint4 g;
    g.x = addpk_bf16(a.x,b.x); g.y = addpk_bf16(a.y,b.y);
    g.z = addpk_bf16(a.z,b.z); g.w = addpk_bf16(a.w,b.w);
    *(uint4*)(gl + er*208 + c16*16) = g;
  }

  // ---- stage / load ef A-fragments
  short8 afr[(K_IN+31)/32];
  if constexpr (K_IN == 96){
    constexpr int RS  = 96*(int)INS::bytes + 16;
    constexpr int CPR = (96*(int)INS::bytes)/16;
    #pragma unroll
    for (int j=0; j*64 < 16*CPR; j++){
      int chunk = j*64 + lane;
      if ((16*CPR) % 64 == 0 || chunk < 16*CPR){
        int er = chunk / CPR, c16 = chunk % CPR;
        int4 v = *(const int4*)((const char*)EF + ((p0+er)*96)*INS::bytes + (size_t)c16*16);
        *(int4*)(myl + er*RS + c16*16) = v;
      }
    }
    #pragma unroll
    for (int kb=0; kb<3; kb++)
      afr[kb] = INS::lds_ld(myl + lo*RS + (kb*32 + q*8)*(int)INS::bytes);
  } else {
    int pe = perm[p0 + lo];
    if (q < 2) afr[0] = INS::ld8(EF + (size_t)pe*K_IN + q*8);
    else       afr[0] = short8{0,0,0,0,0,0,0,0};
  }

  float hsum[3][4] = {{0.f,0.f,0.f,0.f},{0.f,0.f,0.f,0.f},{0.f,0.f,0.f,0.f}};
  constexpr int ORS = 96*(int)OUTS::bytes + 16;

  #pragma unroll
  for (int t=0; t<6; t++){
    int col = t*16 + lo;
    floatx4 acc = {0.f,0.f,0.f,0.f};
    if constexpr (K_IN == 96){
      #pragma unroll
      for (int kb=0; kb<3; kb++){
        short8 b = *(const short8*)(Wt + (size_t)col*96 + kb*32 + q*8);
        acc = __builtin_amdgcn_mfma_f32_16x16x32_bf16(afr[kb], b, acc, 0,0,0);
      }
    } else {
      short8 b = (q<2) ? *(const short8*)(Wt + (size_t)col*16 + q*8)
                       : short8{0,0,0,0,0,0,0,0};
      acc = __builtin_amdgcn_mfma_f32_16x16x32_bf16(afr[0], b, acc, 0,0,0);
    }
    float aw = attn[col];
    float bv = bias[col];
    #pragma unroll
    for (int r=0;r<4;r++){
      float gv = b2f(*(const bf16*)(gl + (q*4+r)*208 + col*2));
      float pre = acc[r] + gv + bv;
      if constexpr (STORE_EF)
        OUTS::lds_st(myl + (q*4+r)*ORS + col*(int)OUTS::bytes, fmaxf(pre, 0.f));
      float lk = pre > 0.f ? pre : 0.01f*pre;
      hsum[t>>1][r] += lk*aw;
    }
  }

  // reduce logits within each 16-lane group; all 16 lanes end with every (h,r) sum
  float red[3][4];
  #pragma unroll
  for (int h=0;h<3;h++){
    #pragma unroll
    for (int r=0;r<4;r++){
      float v = hsum[h][r];
      v += __shfl_xor(v,1);
      v += __shfl_xor(v,2);
      v += __shfl_xor(v,4);
      v += __shfl_xor(v,8);
      red[h][r] = v;
    }
  }
  // lanes lo<12 each own one (h,r): stage logit + atomicMax into per-node table
  {
    float sel = red[0][0];
    #pragma unroll
    for (int h=0;h<3;h++)
      #pragma unroll
      for (int r=0;r<4;r++)
        if (h*4+r != 0) sel = (lo == h*4+r) ? red[h][r] : sel;
    if (lo < 12){
      int hh = lo >> 2, rr = lo & 3;
      lstage[wave][(q*4+rr)*3 + hh] = sel;
      int e = perm[p0 + q*4 + rr];
      int n = clampi(dst[e], N_NODES);
      atomicMax((unsigned*)((char*)nfmax + (size_t)n*192 + 180 + hh*4), fkey(sel));
    }
  }
  if (lane < 12){
    float4 v = *(const float4*)(&lstage[wave][lane*4]);
    *(float4*)((char*)logits + p0*12 + (size_t)lane*16) = v;
  }

  if constexpr (STORE_EF){
    constexpr int OCPR = (96*(int)OUTS::bytes)/16;
    #pragma unroll
    for (int j=0; j*64 < 16*OCPR; j++){
      int chunk = j*64 + lane;
      if ((16*OCPR) % 64 == 0 || chunk < 16*OCPR){
        int er = chunk / OCPR, c16 = chunk % OCPR;
        int4 v = *(const int4*)(myl + er*ORS + c16*16);
        *(int4*)((char*)EFO + ((p0+er)*96)*OUTS::bytes + (size_t)c16*16) = v;
      }
    }
  }
}

// ---------------- single-pass softmax+aggregate: ONE WAVE PER NODE ----------------
// logits contiguous per node (sorted layout); max pre-reduced in nfmax (overlaid on nf rows).
template<bool RELU>
__global__ __launch_bounds__(256) void k_agg3(
    const float* __restrict__ logits,
    const bf16* __restrict__ HS,
    const int* __restrict__ src,
    const int* __restrict__ row_ptr, const int* __restrict__ perm,
    const unsigned* nfmax, bf16* nf_out)
{
  int wave = threadIdx.x >> 6, lane = threadIdx.x & 63;
  int node = blockIdx.x*4 + wave;
  if (node >= N_NODES || lane >= 48) return;
  int r0 = row_ptr[node], r1 = row_ptr[node+1];
  float ox = 0.f, oy = 0.f;
  if (r1 > r0){
    int h = (2*lane) >> 5;
    unsigned k = *(const unsigned*)((const char*)nfmax + (size_t)node*192 + 180 + h*4);
    float m = funkey(k);
    float ax = 0.f, ay = 0.f, ss = 0.f;
    #pragma unroll 4
    for (int i = r0; i < r1; i++){
      float al = __expf(logits[(size_t)i*3 + h] - m);
      int e = perm[i];
      unsigned w = *(const unsigned*)((const char*)HS + (size_t)clampi(src[e],N_NODES)*192 + lane*4);
      float x = __builtin_bit_cast(float, w << 16);
      float y = __builtin_bit_cast(float, w & 0xffff0000u);
      ax += al*x; ay += al*y; ss += al;
    }
    float invs = 1.0f/ss;
    ox = ax*invs; oy = ay*invs;
    if (RELU){ ox = fmaxf(ox,0.f); oy = fmaxf(oy,0.f); }
  }
  unsigned lo16 = (unsigned)(unsigned short)f2bs(ox);
  unsigned hi16 = (unsigned)(unsigned short)f2bs(oy);
  *(unsigned*)((char*)nf_out + (size_t)node*192 + lane*4) = lo16 | (hi16<<16);
}

// ---------------- output gather (f32 out) ----------------
__global__ void k_gather(const bf16* __restrict__ nf, const int* __restrict__ idxs,
                         float* __restrict__ out){
  int t = blockIdx.x*blockDim.x + threadIdx.x;
  if (t < NSEL*F){
    int i = t / F, c = t % F;
    out[t] = b2f(nf[(size_t)clampi(idxs[i], N_NODES)*F + c]);
  }
}

// ---------------- driver ----------------
template<class EFS>
static void run_all(const float* ndata, const float* odfeat, const int* src, const int* dst,
                    const int* idxs,
                    const float* Wns0, const float* Wni0, const float* Wfij0, const float* Wnj0,
                    const float* attn0, const float* bias0,
                    const float* WnsL, const float* WniL, const float* WfijL, const float* WnjL,
                    const float* attnL, const float* biasL,
                    float* out, char* ws, hipStream_t stream)
{
  size_t off = 0;
  auto alloc = [&](size_t bytes)->char*{
    char* p = ws + off; off += (bytes + 255) & ~(size_t)255; return p;
  };
  typename EFS::T* ef = (typename EFS::T*)alloc((size_t)N_EDGES*F*EFS::bytes);
  bf16* NI      = (bf16*)alloc((size_t)N_NODES*F*2);
  bf16* NJ      = (bf16*)alloc((size_t)N_NODES*F*2);
  bf16* HS      = (bf16*)alloc((size_t)N_NODES*F*2);
  bf16* nf      = (bf16*)alloc((size_t)N_NODES*F*2);
  float* logits = (float*)alloc((size_t)N_EDGES*3*4);
  int*  row_ptr = (int*)alloc((size_t)(N_NODES+1)*4);
  int*  counts  = (int*)alloc((size_t)N_NODES*4);
  int*  cursor  = (int*)alloc((size_t)N_NODES*4);
  int*  csr_e   = (int*)alloc((size_t)N_EDGES*4);
  bf16* Wt      = (bf16*)alloc((size_t)WT_ELEMS*2);
  unsigned* nfmax = (unsigned*)nf;   // 12 B per 192-B row, bytes 180..192 (nf dead during edge phase)

  // ---- weight prep (bf16, transposed [c][k])
  WP wp;
  wp.p[0]=Wni0; wp.p[1]=Wnj0; wp.p[2]=Wns0;
  wp.p[3]=WniL; wp.p[4]=WnjL; wp.p[5]=WnsL; wp.p[6]=WfijL;
  wp.p[7]=WniL+9216; wp.p[8]=WnjL+9216; wp.p[9]=WnsL+9216; wp.p[10]=WfijL+9216;
  wp.p[11]=Wfij0;
  k_prep<<<(WT_ELEMS+255)/256, 256, 0, stream>>>(wp, Wt);

  // ---- CSR by dst (perm = csr_e)
  hipMemsetAsync(counts, 0, (size_t)N_NODES*4, stream);
  hipMemsetAsync(cursor, 0, (size_t)N_NODES*4, stream);
  k_count<<<(N_EDGES+255)/256, 256, 0, stream>>>(dst, counts);
  k_scan<<<1, 1024, 0, stream>>>(counts, row_ptr);
  k_fill<<<(N_EDGES+255)/256, 256, 0, stream>>>(dst, row_ptr, cursor, csr_e);

  dim3 ngrid((N_NODES + 63)/64, F/16, 3);
  int  egrid = N_EDGES/64;
  int  agrid = (N_NODES + 3)/4;
  int  mgrid = (N_NODES*3 + 255)/256;

  const bf16 *WtNI0 = Wt,          *WtNJ0 = Wt+9216,   *WtNS0 = Wt+18432;
  const bf16 *WtNI1 = Wt+3*9216,   *WtNJ1 = Wt+4*9216, *WtNS1 = Wt+5*9216, *WtE1 = Wt+6*9216;
  const bf16 *WtNI2 = Wt+7*9216,   *WtNJ2 = Wt+8*9216, *WtNS2 = Wt+9*9216, *WtE2 = Wt+10*9216;
  const bf16 *WtE0  = Wt+11*9216;

  // ---- layer 0
  k_node_gemm<F32S><<<ngrid, 256, 0, stream>>>(ndata, WtNI0, WtNJ0, WtNS0, NI, NJ, HS);
  k_maxinit<<<mgrid, 256, 0, stream>>>(nfmax);
  k_edge5<K_ODF, true, F32S, EFS><<<egrid, 256, 0, stream>>>(
      odfeat, WtE0, NI, NJ, bias0, attn0, src, dst, csr_e, ef, logits, nfmax);
  k_agg3<true><<<agrid, 256, 0, stream>>>(logits, HS, src, row_ptr, csr_e, nfmax, nf);

  // ---- layer 1 (ef updated in place, sorted layout)
  k_node_gemm<BF16S><<<ngrid, 256, 0, stream>>>(nf, WtNI1, WtNJ1, WtNS1, NI, NJ, HS);
  k_maxinit<<<mgrid, 256, 0, stream>>>(nfmax);
  k_edge5<F, true, EFS, EFS><<<egrid, 256, 0, stream>>>(
      ef, WtE1, NI, NJ, biasL, attnL, src, dst, csr_e, ef, logits, nfmax);
  k_agg3<true><<<agrid, 256, 0, stream>>>(logits, HS, src, row_ptr, csr_e, nfmax, nf);

  // ---- layer 2 (no relu on nh, ef not stored)
  k_node_gemm<BF16S><<<ngrid, 256, 0, stream>>>(nf, WtNI2, WtNJ2, WtNS2, NI, NJ, HS);
  k_maxinit<<<mgrid, 256, 0, stream>>>(nfmax);
  k_edge5<F, false, EFS, EFS><<<egrid, 256, 0, stream>>>(
      ef, WtE2, NI, NJ, biasL+F, attnL+F, src, dst, csr_e, (typename EFS::T*)nullptr, logits, nfmax);
  k_agg3<false><<<agrid, 256, 0, stream>>>(logits, HS, src, row_ptr, csr_e, nfmax, nf);

  // ---- output gather
  k_gather<<<(NSEL*F + 255)/256, 256, 0, stream>>>(nf, idxs, out);
}

extern "C" void kernel_launch(void* const* d_in, const int* in_sizes, int n_in,
                              void* d_out, int out_size, void* d_ws, size_t ws_size,
                              hipStream_t stream)
{
  (void)in_sizes; (void)n_in; (void)out_size;
  const float* ndata  = (const float*)d_in[0];
  const float* odfeat = (const float*)d_in[1];
  const int*   src    = (const int*)d_in[2];
  const int*   dst    = (const int*)d_in[3];
  const int*   idxs   = (const int*)d_in[4];
  const float* Wns0   = (const float*)d_in[5];
  const float* Wni0   = (const float*)d_in[6];
  const float* Wfij0  = (const float*)d_in[7];
  const float* Wnj0   = (const float*)d_in[8];
  const float* attn0  = (const float*)d_in[9];
  const float* bias0  = (const float*)d_in[10];
  const float* WnsL   = (const float*)d_in[11];
  const float* WniL   = (const float*)d_in[12];
  const float* WfijL  = (const float*)d_in[13];
  const float* WnjL   = (const float*)d_in[14];
  const float* attnL  = (const float*)d_in[15];
  const float* biasL  = (const float*)d_in[16];

  // bf16-ef plan needs ~205.7 MB of ws; fp8-ef plan needs ~129 MB.
  bool planA = ws_size >= (size_t)206000000;
  if (planA)
    run_all<BF16S>(ndata, odfeat, src, dst, idxs, Wns0, Wni0, Wfij0, Wnj0, attn0, bias0,
                   WnsL, WniL, WfijL, WnjL, attnL, biasL,
                   (float*)d_out, (char*)d_ws, stream);
  else
    run_all<FP8S>(ndata, odfeat, src, dst, idxs, Wns0, Wni0, Wfij0, Wnj0, attn0, bias0,
                  WnsL, WniL, WfijL, WnjL, attnL, biasL,
                  (float*)d_out, (char*)d_ws, stream);
}

// Round 8
// 875.624 us; speedup vs baseline: 1.2671x; 1.2671x over previous
//
#include <hip/hip_runtime.h>
#include <hip/hip_bf16.h>
#include <cstdint>
#include <cstddef>

#define N_NODES 50000
#define N_EDGES 800000
#define NSEL    4096
#define F       96     // H*HN == H*HE
#define K_ODF   16

typedef __attribute__((ext_vector_type(8))) short  short8;
typedef __attribute__((ext_vector_type(4))) float  floatx4;

using bf16 = __hip_bfloat16;

__device__ inline float b2f(bf16 x){ return __bfloat162float(x); }
__device__ inline bf16  f2b(float x){ return __float2bfloat16(x); }
__device__ inline short f2bs(float x){ return __builtin_bit_cast(short, __float2bfloat16(x)); }
__device__ inline int clampi(int v, int hi){ return v < 0 ? 0 : (v >= hi ? hi-1 : v); }

// packed bf16 add: (a.lo+b.lo, a.hi+b.hi) with RNE via f32
__device__ inline unsigned int addpk_bf16(unsigned int a, unsigned int b){
  float alo = __builtin_bit_cast(float, a<<16);
  float ahi = __builtin_bit_cast(float, a & 0xffff0000u);
  float blo = __builtin_bit_cast(float, b<<16);
  float bhi = __builtin_bit_cast(float, b & 0xffff0000u);
  unsigned int pl = (unsigned int)(unsigned short)f2bs(alo+blo);
  unsigned int ph = (unsigned int)(unsigned short)f2bs(ahi+bhi);
  return pl | (ph<<16);
}

// ---------------- storage policies ----------------
struct F32S {
  using T = float;
  static constexpr size_t bytes = 4;
  static __device__ short8 ld8(const T* p){
    float4 u = *(const float4*)p;
    float4 v = *(const float4*)(p+4);
    short8 r;
    r[0]=f2bs(u.x); r[1]=f2bs(u.y); r[2]=f2bs(u.z); r[3]=f2bs(u.w);
    r[4]=f2bs(v.x); r[5]=f2bs(v.y); r[6]=f2bs(v.z); r[7]=f2bs(v.w);
    return r;
  }
  static __device__ short8 lds_ld(const char*){ return short8{0,0,0,0,0,0,0,0}; }
  static __device__ void lds_st(char*, float){}
};
struct BF16S {
  using T = bf16;
  static constexpr size_t bytes = 2;
  static __device__ short8 ld8(const T* p){ return *(const short8*)p; }
  static __device__ short8 lds_ld(const char* p){ return *(const short8*)p; }
  static __device__ void lds_st(char* p, float v){ *(bf16*)p = f2b(v); }
};
struct FP8S {
  using T = unsigned char;
  static constexpr size_t bytes = 1;
  static __device__ short8 cvt8(int2 w){
    short8 r;
    r[0]=f2bs(__builtin_amdgcn_cvt_f32_fp8(w.x,0));
    r[1]=f2bs(__builtin_amdgcn_cvt_f32_fp8(w.x,1));
    r[2]=f2bs(__builtin_amdgcn_cvt_f32_fp8(w.x,2));
    r[3]=f2bs(__builtin_amdgcn_cvt_f32_fp8(w.x,3));
    r[4]=f2bs(__builtin_amdgcn_cvt_f32_fp8(w.y,0));
    r[5]=f2bs(__builtin_amdgcn_cvt_f32_fp8(w.y,1));
    r[6]=f2bs(__builtin_amdgcn_cvt_f32_fp8(w.y,2));
    r[7]=f2bs(__builtin_amdgcn_cvt_f32_fp8(w.y,3));
    return r;
  }
  static __device__ short8 ld8(const T* p){ return cvt8(*(const int2*)p); }
  static __device__ short8 lds_ld(const char* p){ return cvt8(*(const int2*)p); }
  static __device__ void lds_st(char* p, float v){
    int pk = __builtin_amdgcn_cvt_pk_fp8_f32(v, 0.f, 0, false);
    *(unsigned char*)p = (unsigned char)(pk & 0xff);
  }
};

// ---------------- weight prep: bf16 transposed Wt[c][k] ----------------
struct WP { const float* p[12]; };
#define WT_ELEMS (11*9216 + 1536)

__global__ void k_prep(WP w, bf16* __restrict__ Wt){
  int g = blockIdx.x*blockDim.x + threadIdx.x;
  if (g >= WT_ELEMS) return;
  float v;
  if (g < 11*9216){
    int id = g / 9216, s = g % 9216;
    int c = s / 96, k = s % 96;
    v = w.p[id][k*96 + c];
  } else {
    int s = g - 11*9216;
    int c = s / 16, k = s % 16;
    v = w.p[11][k*96 + c];
  }
  Wt[g] = f2b(v);
}

// ---------------- CSR build ----------------
__global__ void k_count(const int* __restrict__ dst, int* __restrict__ counts){
  int e = blockIdx.x*blockDim.x + threadIdx.x;
  if (e < N_EDGES) atomicAdd(&counts[clampi(dst[e], N_NODES)], 1);
}

__global__ void k_scan(const int* __restrict__ counts, int* __restrict__ row_ptr){
  const int T = 1024;
  const int n = N_NODES;
  int tid = threadIdx.x;
  int seg = (n + T - 1)/T;
  int start = tid*seg;
  int end = (start+seg < n) ? start+seg : n;
  int s = 0;
  for (int i=start;i<end;i++) s += counts[i];
  __shared__ int wsums[16];
  int lane = tid & 63, wid = tid >> 6;
  int v = s;
  #pragma unroll
  for (int off=1; off<64; off<<=1){
    int t = __shfl_up(v, off);
    if (lane >= off) v += t;
  }
  if (lane==63) wsums[wid] = v;
  __syncthreads();
  if (wid==0 && lane < 16){
    int w = wsums[lane];
    #pragma unroll
    for (int off=1; off<16; off<<=1){
      int t = __shfl_up(w, off);
      if (lane>=off) w += t;
    }
    wsums[lane] = w;
  }
  __syncthreads();
  int base = (wid>0 ? wsums[wid-1] : 0) + (v - s);
  int run = base;
  for (int i=start;i<end;i++){ row_ptr[i] = run; run += counts[i]; }
  if (tid==T-1) row_ptr[n] = run;
}

__global__ void k_fill(const int* __restrict__ dst, const int* __restrict__ row_ptr,
                       int* __restrict__ cursor, int* __restrict__ csr_e){
  int e = blockIdx.x*blockDim.x + threadIdx.x;
  if (e < N_EDGES){
    int t = clampi(dst[e], N_NODES);
    int pos = atomicAdd(&cursor[t], 1);
    int idx = row_ptr[t] + pos;
    if (idx >= 0 && idx < N_EDGES) csr_e[idx] = e;
  }
}

// ---------------- node GEMM: O = A @ W  (W from transposed bf16 Wt) ----------------
template<class AS>
__global__ __launch_bounds__(256) void k_node_gemm(
    const typename AS::T* A,
    const bf16* __restrict__ Wt_ni, const bf16* __restrict__ Wt_nj, const bf16* __restrict__ Wt_ns,
    bf16* __restrict__ NI, bf16* __restrict__ NJ, bf16* __restrict__ HS)
{
  const bf16* Wt; bf16* O;
  if (blockIdx.z==0){ Wt=Wt_ni; O=NI; } else if (blockIdx.z==1){ Wt=Wt_nj; O=NJ; } else { Wt=Wt_ns; O=HS; }
  int wave = threadIdx.x >> 6, lane = threadIdx.x & 63;
  int lo = lane & 15, q = lane >> 4;
  int m0 = (blockIdx.x*4 + wave)*16;
  int n0 = blockIdx.y*16;
  int row = m0 + lo; if (row >= N_NODES) row = N_NODES-1;
  floatx4 acc = {0.f,0.f,0.f,0.f};
  #pragma unroll
  for (int kb=0; kb<3; kb++){
    int k0 = kb*32 + q*8;
    short8 a = AS::ld8(A + (size_t)row*F + k0);
    short8 b = *(const short8*)(Wt + (size_t)(n0+lo)*96 + k0);
    acc = __builtin_amdgcn_mfma_f32_16x16x32_bf16(a,b,acc,0,0,0);
  }
  #pragma unroll
  for (int r=0;r<4;r++){
    int m = m0 + q*4 + r;
    if (m < N_NODES) O[(size_t)m*F + n0+lo] = f2b(acc[r]);
  }
}

// ---------------- fused edge kernel v6: CSR-sorted positions, NO atomics ----------------
// position p -> edge perm[p]. ef/logits stored at positions (linear).
// layer0 input EF is odfeat in ORIGINAL edge order (gathered via perm).
template<int K_IN, bool STORE_EF, class INS, class OUTS>
__global__ __launch_bounds__(256) void k_edge6(
    const typename INS::T* EF, const bf16* __restrict__ Wt,
    const bf16* __restrict__ NI, const bf16* __restrict__ NJ,
    const float* __restrict__ bias, const float* __restrict__ attn,
    const int* __restrict__ src, const int* __restrict__ dst,
    const int* __restrict__ perm,
    typename OUTS::T* EFO, float* __restrict__ logits)
{
  __shared__ __align__(16) char lds_ef[4][3328];
  __shared__ __align__(16) char lds_g[4][3328];
  __shared__ __align__(16) float lstage[4][48];

  int wave = threadIdx.x >> 6, lane = threadIdx.x & 63;
  int lo = lane & 15, q = lane >> 4;
  size_t p0 = ((size_t)blockIdx.x*4 + wave)*16;
  char* myl = lds_ef[wave];
  char* gl  = lds_g[wave];

  // ---- stage G = NI[src]+NJ[dst] (bf16); dst sorted -> NJ rows L1/L2-local
  int eL[3], seL[3], deL[3];
  #pragma unroll
  for (int j=0;j<3;j++) eL[j] = perm[p0 + (j*64+lane)/12];
  #pragma unroll
  for (int j=0;j<3;j++){ seL[j] = clampi(src[eL[j]], N_NODES); deL[j] = clampi(dst[eL[j]], N_NODES); }
  #pragma unroll
  for (int j=0;j<3;j++){
    int chunk = j*64 + lane;
    int er = chunk/12, c16 = chunk - er*12;
    uint4 a = *(const uint4*)((const char*)NI + (size_t)seL[j]*192 + c16*16);
    uint4 b = *(const uint4*)((const char*)NJ + (size_t)deL[j]*192 + c16*16);
    uint4 g;
    g.x = addpk_bf16(a.x,b.x); g.y = addpk_bf16(a.y,b.y);
    g.z = addpk_bf16(a.z,b.z); g.w = addpk_bf16(a.w,b.w);
    *(uint4*)(gl + er*208 + c16*16) = g;
  }

  // ---- stage / load ef A-fragments
  short8 afr[(K_IN+31)/32];
  if constexpr (K_IN == 96){
    constexpr int RS  = 96*(int)INS::bytes + 16;
    constexpr int CPR = (96*(int)INS::bytes)/16;
    #pragma unroll
    for (int j=0; j*64 < 16*CPR; j++){
      int chunk = j*64 + lane;
      if ((16*CPR) % 64 == 0 || chunk < 16*CPR){
        int er = chunk / CPR, c16 = chunk % CPR;
        int4 v = *(const int4*)((const char*)EF + ((p0+er)*96)*INS::bytes + (size_t)c16*16);
        *(int4*)(myl + er*RS + c16*16) = v;
      }
    }
    #pragma unroll
    for (int kb=0; kb<3; kb++)
      afr[kb] = INS::lds_ld(myl + lo*RS + (kb*32 + q*8)*(int)INS::bytes);
  } else {
    int pe = perm[p0 + lo];
    if (q < 2) afr[0] = INS::ld8(EF + (size_t)pe*K_IN + q*8);
    else       afr[0] = short8{0,0,0,0,0,0,0,0};
  }

  float hsum[3][4] = {{0.f,0.f,0.f,0.f},{0.f,0.f,0.f,0.f},{0.f,0.f,0.f,0.f}};
  constexpr int ORS = 96*(int)OUTS::bytes + 16;

  #pragma unroll
  for (int t=0; t<6; t++){
    int col = t*16 + lo;
    floatx4 acc = {0.f,0.f,0.f,0.f};
    if constexpr (K_IN == 96){
      #pragma unroll
      for (int kb=0; kb<3; kb++){
        short8 b = *(const short8*)(Wt + (size_t)col*96 + kb*32 + q*8);
        acc = __builtin_amdgcn_mfma_f32_16x16x32_bf16(afr[kb], b, acc, 0,0,0);
      }
    } else {
      short8 b = (q<2) ? *(const short8*)(Wt + (size_t)col*16 + q*8)
                       : short8{0,0,0,0,0,0,0,0};
      acc = __builtin_amdgcn_mfma_f32_16x16x32_bf16(afr[0], b, acc, 0,0,0);
    }
    float aw = attn[col];
    float bv = bias[col];
    #pragma unroll
    for (int r=0;r<4;r++){
      float gv = b2f(*(const bf16*)(gl + (q*4+r)*208 + col*2));
      float pre = acc[r] + gv + bv;
      if constexpr (STORE_EF)
        OUTS::lds_st(myl + (q*4+r)*ORS + col*(int)OUTS::bytes, fmaxf(pre, 0.f));
      float lk = pre > 0.f ? pre : 0.01f*pre;
      hsum[t>>1][r] += lk*aw;
    }
  }

  // reduce logits within each 16-lane group, stage, store as dwordx4 (linear!)
  #pragma unroll
  for (int h=0;h<3;h++){
    #pragma unroll
    for (int r=0;r<4;r++){
      float v = hsum[h][r];
      v += __shfl_xor(v,1);
      v += __shfl_xor(v,2);
      v += __shfl_xor(v,4);
      v += __shfl_xor(v,8);
      if (lo==0) lstage[wave][(q*4+r)*3 + h] = v;
    }
  }
  if (lane < 12){
    float4 v = *(const float4*)(&lstage[wave][lane*4]);
    *(float4*)((char*)logits + p0*12 + (size_t)lane*16) = v;
  }

  if constexpr (STORE_EF){
    constexpr int OCPR = (96*(int)OUTS::bytes)/16;
    #pragma unroll
    for (int j=0; j*64 < 16*OCPR; j++){
      int chunk = j*64 + lane;
      if ((16*OCPR) % 64 == 0 || chunk < 16*OCPR){
        int er = chunk / OCPR, c16 = chunk % OCPR;
        int4 v = *(const int4*)(myl + er*ORS + c16*16);
        *(int4*)((char*)EFO + ((p0+er)*96)*OUTS::bytes + (size_t)c16*16) = v;
      }
    }
  }
}

// ---------------- softmax+aggregate: ONE WAVE PER NODE, contiguous logits ----------------
// pass 1: max over contiguous per-node logits (coalesced); pass 2: fused exp-sum + weighted HS sum.
template<bool RELU>
__global__ __launch_bounds__(256) void k_agg4(
    const float* __restrict__ logits,
    const bf16* __restrict__ HS,
    const int* __restrict__ src,
    const int* __restrict__ row_ptr, const int* __restrict__ perm,
    bf16* nf_out)
{
  int wave = threadIdx.x >> 6, lane = threadIdx.x & 63;
  int node = blockIdx.x*4 + wave;
  if (node >= N_NODES) return;
  int r0 = row_ptr[node], r1 = row_ptr[node+1];

  // pass 1: per-head max over contiguous logits rows (12 B per edge)
  float m0=-3.0e38f, m1=-3.0e38f, m2=-3.0e38f;
  for (int i = r0 + lane; i < r1; i += 64){
    const float* lp = logits + (size_t)i*3;
    m0 = fmaxf(m0, lp[0]);
    m1 = fmaxf(m1, lp[1]);
    m2 = fmaxf(m2, lp[2]);
  }
  #pragma unroll
  for (int o=1;o<64;o<<=1){
    m0 = fmaxf(m0, __shfl_xor(m0,o));
    m1 = fmaxf(m1, __shfl_xor(m1,o));
    m2 = fmaxf(m2, __shfl_xor(m2,o));
  }

  // pass 2: 48 lanes own one dword (2 cols) of the 192-B output row
  if (lane >= 48) return;
  float ox = 0.f, oy = 0.f;
  if (r1 > r0){
    int h = (2*lane) >> 5;
    float mm = (h==0) ? m0 : (h==1 ? m1 : m2);
    float ax = 0.f, ay = 0.f, ss = 0.f;
    #pragma unroll 4
    for (int i = r0; i < r1; i++){
      float al = __expf(logits[(size_t)i*3 + h] - mm);
      int e = perm[i];
      unsigned w = *(const unsigned*)((const char*)HS + (size_t)clampi(src[e],N_NODES)*192 + lane*4);
      float x = __builtin_bit_cast(float, w << 16);
      float y = __builtin_bit_cast(float, w & 0xffff0000u);
      ax += al*x; ay += al*y; ss += al;
    }
    float invs = 1.0f/ss;
    ox = ax*invs; oy = ay*invs;
    if (RELU){ ox = fmaxf(ox,0.f); oy = fmaxf(oy,0.f); }
  }
  unsigned lo16 = (unsigned)(unsigned short)f2bs(ox);
  unsigned hi16 = (unsigned)(unsigned short)f2bs(oy);
  *(unsigned*)((char*)nf_out + (size_t)node*192 + lane*4) = lo16 | (hi16<<16);
}

// ---------------- output gather (f32 out) ----------------
__global__ void k_gather(const bf16* __restrict__ nf, const int* __restrict__ idxs,
                         float* __restrict__ out){
  int t = blockIdx.x*blockDim.x + threadIdx.x;
  if (t < NSEL*F){
    int i = t / F, c = t % F;
    out[t] = b2f(nf[(size_t)clampi(idxs[i], N_NODES)*F + c]);
  }
}

// ---------------- driver ----------------
template<class EFS>
static void run_all(const float* ndata, const float* odfeat, const int* src, const int* dst,
                    const int* idxs,
                    const float* Wns0, const float* Wni0, const float* Wfij0, const float* Wnj0,
                    const float* attn0, const float* bias0,
                    const float* WnsL, const float* WniL, const float* WfijL, const float* WnjL,
                    const float* attnL, const float* biasL,
                    float* out, char* ws, hipStream_t stream)
{
  size_t off = 0;
  auto alloc = [&](size_t bytes)->char*{
    char* p = ws + off; off += (bytes + 255) & ~(size_t)255; return p;
  };
  typename EFS::T* ef = (typename EFS::T*)alloc((size_t)N_EDGES*F*EFS::bytes);
  bf16* NI      = (bf16*)alloc((size_t)N_NODES*F*2);
  bf16* NJ      = (bf16*)alloc((size_t)N_NODES*F*2);
  bf16* HS      = (bf16*)alloc((size_t)N_NODES*F*2);
  bf16* nf      = (bf16*)alloc((size_t)N_NODES*F*2);
  float* logits = (float*)alloc((size_t)N_EDGES*3*4);
  int*  row_ptr = (int*)alloc((size_t)(N_NODES+1)*4);
  int*  counts  = (int*)alloc((size_t)N_NODES*4);
  int*  cursor  = (int*)alloc((size_t)N_NODES*4);
  int*  csr_e   = (int*)alloc((size_t)N_EDGES*4);
  bf16* Wt      = (bf16*)alloc((size_t)WT_ELEMS*2);

  // ---- weight prep (bf16, transposed [c][k])
  WP wp;
  wp.p[0]=Wni0; wp.p[1]=Wnj0; wp.p[2]=Wns0;
  wp.p[3]=WniL; wp.p[4]=WnjL; wp.p[5]=WnsL; wp.p[6]=WfijL;
  wp.p[7]=WniL+9216; wp.p[8]=WnjL+9216; wp.p[9]=WnsL+9216; wp.p[10]=WfijL+9216;
  wp.p[11]=Wfij0;
  k_prep<<<(WT_ELEMS+255)/256, 256, 0, stream>>>(wp, Wt);

  // ---- CSR by dst (perm = csr_e)
  hipMemsetAsync(counts, 0, (size_t)N_NODES*4, stream);
  hipMemsetAsync(cursor, 0, (size_t)N_NODES*4, stream);
  k_count<<<(N_EDGES+255)/256, 256, 0, stream>>>(dst, counts);
  k_scan<<<1, 1024, 0, stream>>>(counts, row_ptr);
  k_fill<<<(N_EDGES+255)/256, 256, 0, stream>>>(dst, row_ptr, cursor, csr_e);

  dim3 ngrid((N_NODES + 63)/64, F/16, 3);
  int  egrid = N_EDGES/64;
  int  agrid = (N_NODES + 3)/4;

  const bf16 *WtNI0 = Wt,          *WtNJ0 = Wt+9216,   *WtNS0 = Wt+18432;
  const bf16 *WtNI1 = Wt+3*9216,   *WtNJ1 = Wt+4*9216, *WtNS1 = Wt+5*9216, *WtE1 = Wt+6*9216;
  const bf16 *WtNI2 = Wt+7*9216,   *WtNJ2 = Wt+8*9216, *WtNS2 = Wt+9*9216, *WtE2 = Wt+10*9216;
  const bf16 *WtE0  = Wt+11*9216;

  // ---- layer 0
  k_node_gemm<F32S><<<ngrid, 256, 0, stream>>>(ndata, WtNI0, WtNJ0, WtNS0, NI, NJ, HS);
  k_edge6<K_ODF, true, F32S, EFS><<<egrid, 256, 0, stream>>>(
      odfeat, WtE0, NI, NJ, bias0, attn0, src, dst, csr_e, ef, logits);
  k_agg4<true><<<agrid, 256, 0, stream>>>(logits, HS, src, row_ptr, csr_e, nf);

  // ---- layer 1 (ef updated in place, sorted layout)
  k_node_gemm<BF16S><<<ngrid, 256, 0, stream>>>(nf, WtNI1, WtNJ1, WtNS1, NI, NJ, HS);
  k_edge6<F, true, EFS, EFS><<<egrid, 256, 0, stream>>>(
      ef, WtE1, NI, NJ, biasL, attnL, src, dst, csr_e, ef, logits);
  k_agg4<true><<<agrid, 256, 0, stream>>>(logits, HS, src, row_ptr, csr_e, nf);

  // ---- layer 2 (no relu on nh, ef not stored)
  k_node_gemm<BF16S><<<ngrid, 256, 0, stream>>>(nf, WtNI2, WtNJ2, WtNS2, NI, NJ, HS);
  k_edge6<F, false, EFS, EFS><<<egrid, 256, 0, stream>>>(
      ef, WtE2, NI, NJ, biasL+F, attnL+F, src, dst, csr_e, (typename EFS::T*)nullptr, logits);
  k_agg4<false><<<agrid, 256, 0, stream>>>(logits, HS, src, row_ptr, csr_e, nf);

  // ---- output gather
  k_gather<<<(NSEL*F + 255)/256, 256, 0, stream>>>(nf, idxs, out);
}

extern "C" void kernel_launch(void* const* d_in, const int* in_sizes, int n_in,
                              void* d_out, int out_size, void* d_ws, size_t ws_size,
                              hipStream_t stream)
{
  (void)in_sizes; (void)n_in; (void)out_size;
  const float* ndata  = (const float*)d_in[0];
  const float* odfeat = (const float*)d_in[1];
  const int*   src    = (const int*)d_in[2];
  const int*   dst    = (const int*)d_in[3];
  const int*   idxs   = (const int*)d_in[4];
  const float* Wns0   = (const float*)d_in[5];
  const float* Wni0   = (const float*)d_in[6];
  const float* Wfij0  = (const float*)d_in[7];
  const float* Wnj0   = (const float*)d_in[8];
  const float* attn0  = (const float*)d_in[9];
  const float* bias0  = (const float*)d_in[10];
  const float* WnsL   = (const float*)d_in[11];
  const float* WniL   = (const float*)d_in[12];
  const float* WfijL  = (const float*)d_in[13];
  const float* WnjL   = (const float*)d_in[14];
  const float* attnL  = (const float*)d_in[15];
  const float* biasL  = (const float*)d_in[16];

  // bf16-ef plan needs ~205.7 MB of ws; fp8-ef plan needs ~129 MB.
  bool planA = ws_size >= (size_t)206000000;
  if (planA)
    run_all<BF16S>(ndata, odfeat, src, dst, idxs, Wns0, Wni0, Wfij0, Wnj0, attn0, bias0,
                   WnsL, WniL, WfijL, WnjL, attnL, biasL,
                   (float*)d_out, (char*)d_ws, stream);
  else
    run_all<FP8S>(ndata, odfeat, src, dst, idxs, Wns0, Wni0, Wfij0, Wnj0, attn0, bias0,
                  WnsL, WniL, WfijL, WnjL, attnL, biasL,
                  (float*)d_out, (char*)d_ws, stream);
}

// Round 9
// 851.429 us; speedup vs baseline: 1.3031x; 1.0284x over previous
//
#include <hip/hip_runtime.h>
#include <hip/hip_bf16.h>
#include <cstdint>
#include <cstddef>

#define N_NODES 50000
#define N_EDGES 800000
#define NSEL    4096
#define F       96     // H*HN == H*HE
#define K_ODF   16

typedef __attribute__((ext_vector_type(8))) short  short8;
typedef __attribute__((ext_vector_type(4))) float  floatx4;

using bf16 = __hip_bfloat16;

__device__ inline float b2f(bf16 x){ return __bfloat162float(x); }
__device__ inline bf16  f2b(float x){ return __float2bfloat16(x); }
__device__ inline short f2bs(float x){ return __builtin_bit_cast(short, __float2bfloat16(x)); }
__device__ inline int clampi(int v, int hi){ return v < 0 ? 0 : (v >= hi ? hi-1 : v); }

// packed bf16 add: (a.lo+b.lo, a.hi+b.hi) with RNE via f32
__device__ inline unsigned int addpk_bf16(unsigned int a, unsigned int b){
  float alo = __builtin_bit_cast(float, a<<16);
  float ahi = __builtin_bit_cast(float, a & 0xffff0000u);
  float blo = __builtin_bit_cast(float, b<<16);
  float bhi = __builtin_bit_cast(float, b & 0xffff0000u);
  unsigned int pl = (unsigned int)(unsigned short)f2bs(alo+blo);
  unsigned int ph = (unsigned int)(unsigned short)f2bs(ahi+bhi);
  return pl | (ph<<16);
}

// ---------------- storage policies ----------------
struct F32S {
  using T = float;
  static constexpr size_t bytes = 4;
  static __device__ short8 ld8(const T* p){
    float4 u = *(const float4*)p;
    float4 v = *(const float4*)(p+4);
    short8 r;
    r[0]=f2bs(u.x); r[1]=f2bs(u.y); r[2]=f2bs(u.z); r[3]=f2bs(u.w);
    r[4]=f2bs(v.x); r[5]=f2bs(v.y); r[6]=f2bs(v.z); r[7]=f2bs(v.w);
    return r;
  }
  static __device__ short8 lds_ld(const char*){ return short8{0,0,0,0,0,0,0,0}; }
  static __device__ void lds_st(char*, float){}
};
struct BF16S {
  using T = bf16;
  static constexpr size_t bytes = 2;
  static __device__ short8 ld8(const T* p){ return *(const short8*)p; }
  static __device__ short8 lds_ld(const char* p){ return *(const short8*)p; }
  static __device__ void lds_st(char* p, float v){ *(bf16*)p = f2b(v); }
};
struct FP8S {
  using T = unsigned char;
  static constexpr size_t bytes = 1;
  static __device__ short8 cvt8(int2 w){
    short8 r;
    r[0]=f2bs(__builtin_amdgcn_cvt_f32_fp8(w.x,0));
    r[1]=f2bs(__builtin_amdgcn_cvt_f32_fp8(w.x,1));
    r[2]=f2bs(__builtin_amdgcn_cvt_f32_fp8(w.x,2));
    r[3]=f2bs(__builtin_amdgcn_cvt_f32_fp8(w.x,3));
    r[4]=f2bs(__builtin_amdgcn_cvt_f32_fp8(w.y,0));
    r[5]=f2bs(__builtin_amdgcn_cvt_f32_fp8(w.y,1));
    r[6]=f2bs(__builtin_amdgcn_cvt_f32_fp8(w.y,2));
    r[7]=f2bs(__builtin_amdgcn_cvt_f32_fp8(w.y,3));
    return r;
  }
  static __device__ short8 ld8(const T* p){ return cvt8(*(const int2*)p); }
  static __device__ short8 lds_ld(const char* p){ return cvt8(*(const int2*)p); }
  static __device__ void lds_st(char* p, float v){
    int pk = __builtin_amdgcn_cvt_pk_fp8_f32(v, 0.f, 0, false);
    *(unsigned char*)p = (unsigned char)(pk & 0xff);
  }
};

// ---------------- weight prep: bf16 transposed Wt[c][k] ----------------
struct WP { const float* p[12]; };
#define WT_ELEMS (11*9216 + 1536)

__global__ void k_prep(WP w, bf16* __restrict__ Wt){
  int g = blockIdx.x*blockDim.x + threadIdx.x;
  if (g >= WT_ELEMS) return;
  float v;
  if (g < 11*9216){
    int id = g / 9216, s = g % 9216;
    int c = s / 96, k = s % 96;
    v = w.p[id][k*96 + c];
  } else {
    int s = g - 11*9216;
    int c = s / 16, k = s % 16;
    v = w.p[11][k*96 + c];
  }
  Wt[g] = f2b(v);
}

// ---------------- CSR build ----------------
__global__ void k_count(const int* __restrict__ dst, int* __restrict__ counts){
  int e = blockIdx.x*blockDim.x + threadIdx.x;
  if (e < N_EDGES) atomicAdd(&counts[clampi(dst[e], N_NODES)], 1);
}

__global__ void k_scan(const int* __restrict__ counts, int* __restrict__ row_ptr){
  const int T = 1024;
  const int n = N_NODES;
  int tid = threadIdx.x;
  int seg = (n + T - 1)/T;
  int start = tid*seg;
  int end = (start+seg < n) ? start+seg : n;
  int s = 0;
  for (int i=start;i<end;i++) s += counts[i];
  __shared__ int wsums[16];
  int lane = tid & 63, wid = tid >> 6;
  int v = s;
  #pragma unroll
  for (int off=1; off<64; off<<=1){
    int t = __shfl_up(v, off);
    if (lane >= off) v += t;
  }
  if (lane==63) wsums[wid] = v;
  __syncthreads();
  if (wid==0 && lane < 16){
    int w = wsums[lane];
    #pragma unroll
    for (int off=1; off<16; off<<=1){
      int t = __shfl_up(w, off);
      if (lane>=off) w += t;
    }
    wsums[lane] = w;
  }
  __syncthreads();
  int base = (wid>0 ? wsums[wid-1] : 0) + (v - s);
  int run = base;
  for (int i=start;i<end;i++){ row_ptr[i] = run; run += counts[i]; }
  if (tid==T-1) row_ptr[n] = run;
}

__global__ void k_fill(const int* __restrict__ dst, const int* __restrict__ row_ptr,
                       int* __restrict__ cursor, int* __restrict__ csr_e){
  int e = blockIdx.x*blockDim.x + threadIdx.x;
  if (e < N_EDGES){
    int t = clampi(dst[e], N_NODES);
    int pos = atomicAdd(&cursor[t], 1);
    int idx = row_ptr[t] + pos;
    if (idx >= 0 && idx < N_EDGES) csr_e[idx] = e;
  }
}

// ---------------- node GEMM: O = A @ W  (W from transposed bf16 Wt) ----------------
template<class AS>
__global__ __launch_bounds__(256) void k_node_gemm(
    const typename AS::T* A,
    const bf16* __restrict__ Wt_ni, const bf16* __restrict__ Wt_nj, const bf16* __restrict__ Wt_ns,
    bf16* __restrict__ NI, bf16* __restrict__ NJ, bf16* __restrict__ HS)
{
  const bf16* Wt; bf16* O;
  if (blockIdx.z==0){ Wt=Wt_ni; O=NI; } else if (blockIdx.z==1){ Wt=Wt_nj; O=NJ; } else { Wt=Wt_ns; O=HS; }
  int wave = threadIdx.x >> 6, lane = threadIdx.x & 63;
  int lo = lane & 15, q = lane >> 4;
  int m0 = (blockIdx.x*4 + wave)*16;
  int n0 = blockIdx.y*16;
  int row = m0 + lo; if (row >= N_NODES) row = N_NODES-1;
  floatx4 acc = {0.f,0.f,0.f,0.f};
  #pragma unroll
  for (int kb=0; kb<3; kb++){
    int k0 = kb*32 + q*8;
    short8 a = AS::ld8(A + (size_t)row*F + k0);
    short8 b = *(const short8*)(Wt + (size_t)(n0+lo)*96 + k0);
    acc = __builtin_amdgcn_mfma_f32_16x16x32_bf16(a,b,acc,0,0,0);
  }
  #pragma unroll
  for (int r=0;r<4;r++){
    int m = m0 + q*4 + r;
    if (m < N_NODES) O[(size_t)m*F + n0+lo] = f2b(acc[r]);
  }
}

// ---------------- fused edge kernel v7: CSR-sorted, single LDS buffer (bf16 path) ----------------
// Liveness trick: ef-stage dies once afr regs are loaded; each G slot dies at its
// epilogue read, and the out value for that (row,col) is produced right then ->
// G staged over the ef buffer, out written back into the G slot just read.
// DS ops are in-order per wave (same base array) -> no barriers needed.
template<int K_IN, bool STORE_EF, class INS, class OUTS>
__global__ __launch_bounds__(256) void k_edge7(
    const typename INS::T* EF, const bf16* __restrict__ Wt,
    const bf16* __restrict__ NI, const bf16* __restrict__ NJ,
    const float* __restrict__ bias, const float* __restrict__ attn,
    const int* __restrict__ src, const int* __restrict__ dst,
    const int* __restrict__ perm,
    typename OUTS::T* EFO, float* __restrict__ logits)
{
  constexpr bool ONEBUF = ((int)OUTS::bytes == 2) || !STORE_EF;
  __shared__ __align__(16) char lds_a[4][3328];
  __shared__ __align__(16) char lds_b[4][ONEBUF ? 16 : 3328];
  __shared__ __align__(16) float lstage[4][48];

  int wave = threadIdx.x >> 6, lane = threadIdx.x & 63;
  int lo = lane & 15, q = lane >> 4;
  size_t p0 = ((size_t)blockIdx.x*4 + wave)*16;
  char* myl = lds_a[wave];
  char* gl  = ONEBUF ? myl : lds_b[wave];

  // indices for G staging (issue loads early)
  int eL[3], seL[3], deL[3];
  #pragma unroll
  for (int j=0;j<3;j++) eL[j] = perm[p0 + (j*64+lane)/12];
  #pragma unroll
  for (int j=0;j<3;j++){ seL[j] = clampi(src[eL[j]], N_NODES); deL[j] = clampi(dst[eL[j]], N_NODES); }

  // ---- stage ef + load A-fragments FIRST (buffer freed for G afterwards)
  short8 afr[(K_IN+31)/32];
  if constexpr (K_IN == 96){
    constexpr int RS  = 96*(int)INS::bytes + 16;
    constexpr int CPR = (96*(int)INS::bytes)/16;
    #pragma unroll
    for (int j=0; j*64 < 16*CPR; j++){
      int chunk = j*64 + lane;
      if ((16*CPR) % 64 == 0 || chunk < 16*CPR){
        int er = chunk / CPR, c16 = chunk % CPR;
        int4 v = *(const int4*)((const char*)EF + ((p0+er)*96)*INS::bytes + (size_t)c16*16);
        *(int4*)(myl + er*RS + c16*16) = v;
      }
    }
    #pragma unroll
    for (int kb=0; kb<3; kb++)
      afr[kb] = INS::lds_ld(myl + lo*RS + (kb*32 + q*8)*(int)INS::bytes);
  } else {
    int pe = perm[p0 + lo];
    if (q < 2) afr[0] = INS::ld8(EF + (size_t)pe*K_IN + q*8);
    else       afr[0] = short8{0,0,0,0,0,0,0,0};
  }

  // ---- stage G = NI[src]+NJ[dst] (bf16, stride 208) into gl (may alias myl)
  #pragma unroll
  for (int j=0;j<3;j++){
    int chunk = j*64 + lane;
    int er = chunk/12, c16 = chunk - er*12;
    uint4 a = *(const uint4*)((const char*)NI + (size_t)seL[j]*192 + c16*16);
    uint4 b = *(const uint4*)((const char*)NJ + (size_t)deL[j]*192 + c16*16);
    uint4 g;
    g.x = addpk_bf16(a.x,b.x); g.y = addpk_bf16(a.y,b.y);
    g.z = addpk_bf16(a.z,b.z); g.w = addpk_bf16(a.w,b.w);
    *(uint4*)(gl + er*208 + c16*16) = g;
  }

  float hsum[3][4] = {{0.f,0.f,0.f,0.f},{0.f,0.f,0.f,0.f},{0.f,0.f,0.f,0.f}};
  constexpr int ORS = 96*(int)OUTS::bytes + 16;   // == 208 for bf16 (same as G stride)

  #pragma unroll
  for (int t=0; t<6; t++){
    int col = t*16 + lo;
    floatx4 acc = {0.f,0.f,0.f,0.f};
    if constexpr (K_IN == 96){
      #pragma unroll
      for (int kb=0; kb<3; kb++){
        short8 b = *(const short8*)(Wt + (size_t)col*96 + kb*32 + q*8);
        acc = __builtin_amdgcn_mfma_f32_16x16x32_bf16(afr[kb], b, acc, 0,0,0);
      }
    } else {
      short8 b = (q<2) ? *(const short8*)(Wt + (size_t)col*16 + q*8)
                       : short8{0,0,0,0,0,0,0,0};
      acc = __builtin_amdgcn_mfma_f32_16x16x32_bf16(afr[0], b, acc, 0,0,0);
    }
    float aw = attn[col];
    float bv = bias[col];
    #pragma unroll
    for (int r=0;r<4;r++){
      char* gslot = gl + (q*4+r)*208 + col*2;
      float gv = b2f(*(const bf16*)gslot);
      float pre = acc[r] + gv + bv;
      if constexpr (STORE_EF){
        if constexpr (ONEBUF) *(bf16*)gslot = f2b(fmaxf(pre, 0.f));   // out overwrites dead G slot
        else OUTS::lds_st(myl + (q*4+r)*ORS + col*(int)OUTS::bytes, fmaxf(pre, 0.f));
      }
      float lk = pre > 0.f ? pre : 0.01f*pre;
      hsum[t>>1][r] += lk*aw;
    }
  }

  // reduce logits within each 16-lane group, stage, store as dwordx4 (linear)
  #pragma unroll
  for (int h=0;h<3;h++){
    #pragma unroll
    for (int r=0;r<4;r++){
      float v = hsum[h][r];
      v += __shfl_xor(v,1);
      v += __shfl_xor(v,2);
      v += __shfl_xor(v,4);
      v += __shfl_xor(v,8);
      if (lo==0) lstage[wave][(q*4+r)*3 + h] = v;
    }
  }
  if (lane < 12){
    float4 v = *(const float4*)(&lstage[wave][lane*4]);
    *(float4*)((char*)logits + p0*12 + (size_t)lane*16) = v;
  }

  if constexpr (STORE_EF){
    const char* ob = ONEBUF ? gl : myl;
    constexpr int OCPR = (96*(int)OUTS::bytes)/16;
    #pragma unroll
    for (int j=0; j*64 < 16*OCPR; j++){
      int chunk = j*64 + lane;
      if ((16*OCPR) % 64 == 0 || chunk < 16*OCPR){
        int er = chunk / OCPR, c16 = chunk % OCPR;
        int4 v = *(const int4*)(ob + er*ORS + c16*16);
        *(int4*)((char*)EFO + ((p0+er)*96)*OUTS::bytes + (size_t)c16*16) = v;
      }
    }
  }
}

// ---------------- softmax+aggregate: ONE WAVE PER NODE, contiguous logits ----------------
template<bool RELU>
__global__ __launch_bounds__(256) void k_agg4(
    const float* __restrict__ logits,
    const bf16* __restrict__ HS,
    const int* __restrict__ src,
    const int* __restrict__ row_ptr, const int* __restrict__ perm,
    bf16* nf_out)
{
  int wave = threadIdx.x >> 6, lane = threadIdx.x & 63;
  int node = blockIdx.x*4 + wave;
  if (node >= N_NODES) return;
  int r0 = row_ptr[node], r1 = row_ptr[node+1];

  float m0=-3.0e38f, m1=-3.0e38f, m2=-3.0e38f;
  for (int i = r0 + lane; i < r1; i += 64){
    const float* lp = logits + (size_t)i*3;
    m0 = fmaxf(m0, lp[0]);
    m1 = fmaxf(m1, lp[1]);
    m2 = fmaxf(m2, lp[2]);
  }
  #pragma unroll
  for (int o=1;o<64;o<<=1){
    m0 = fmaxf(m0, __shfl_xor(m0,o));
    m1 = fmaxf(m1, __shfl_xor(m1,o));
    m2 = fmaxf(m2, __shfl_xor(m2,o));
  }

  if (lane >= 48) return;
  float ox = 0.f, oy = 0.f;
  if (r1 > r0){
    int h = (2*lane) >> 5;
    float mm = (h==0) ? m0 : (h==1 ? m1 : m2);
    float ax = 0.f, ay = 0.f, ss = 0.f;
    #pragma unroll 4
    for (int i = r0; i < r1; i++){
      float al = __expf(logits[(size_t)i*3 + h] - mm);
      int e = perm[i];
      unsigned w = *(const unsigned*)((const char*)HS + (size_t)clampi(src[e],N_NODES)*192 + lane*4);
      float x = __builtin_bit_cast(float, w << 16);
      float y = __builtin_bit_cast(float, w & 0xffff0000u);
      ax += al*x; ay += al*y; ss += al;
    }
    float invs = 1.0f/ss;
    ox = ax*invs; oy = ay*invs;
    if (RELU){ ox = fmaxf(ox,0.f); oy = fmaxf(oy,0.f); }
  }
  unsigned lo16 = (unsigned)(unsigned short)f2bs(ox);
  unsigned hi16 = (unsigned)(unsigned short)f2bs(oy);
  *(unsigned*)((char*)nf_out + (size_t)node*192 + lane*4) = lo16 | (hi16<<16);
}

// ---------------- output gather (f32 out) ----------------
__global__ void k_gather(const bf16* __restrict__ nf, const int* __restrict__ idxs,
                         float* __restrict__ out){
  int t = blockIdx.x*blockDim.x + threadIdx.x;
  if (t < NSEL*F){
    int i = t / F, c = t % F;
    out[t] = b2f(nf[(size_t)clampi(idxs[i], N_NODES)*F + c]);
  }
}

// ---------------- driver ----------------
template<class EFS>
static void run_all(const float* ndata, const float* odfeat, const int* src, const int* dst,
                    const int* idxs,
                    const float* Wns0, const float* Wni0, const float* Wfij0, const float* Wnj0,
                    const float* attn0, const float* bias0,
                    const float* WnsL, const float* WniL, const float* WfijL, const float* WnjL,
                    const float* attnL, const float* biasL,
                    float* out, char* ws, hipStream_t stream)
{
  size_t off = 0;
  auto alloc = [&](size_t bytes)->char*{
    char* p = ws + off; off += (bytes + 255) & ~(size_t)255; return p;
  };
  typename EFS::T* ef = (typename EFS::T*)alloc((size_t)N_EDGES*F*EFS::bytes);
  bf16* NI      = (bf16*)alloc((size_t)N_NODES*F*2);
  bf16* NJ      = (bf16*)alloc((size_t)N_NODES*F*2);
  bf16* HS      = (bf16*)alloc((size_t)N_NODES*F*2);
  bf16* nf      = (bf16*)alloc((size_t)N_NODES*F*2);
  float* logits = (float*)alloc((size_t)N_EDGES*3*4);
  int*  row_ptr = (int*)alloc((size_t)(N_NODES+1)*4);
  int*  counts  = (int*)alloc((size_t)N_NODES*4);
  int*  cursor  = (int*)alloc((size_t)N_NODES*4);
  int*  csr_e   = (int*)alloc((size_t)N_EDGES*4);
  bf16* Wt      = (bf16*)alloc((size_t)WT_ELEMS*2);

  // ---- weight prep (bf16, transposed [c][k])
  WP wp;
  wp.p[0]=Wni0; wp.p[1]=Wnj0; wp.p[2]=Wns0;
  wp.p[3]=WniL; wp.p[4]=WnjL; wp.p[5]=WnsL; wp.p[6]=WfijL;
  wp.p[7]=WniL+9216; wp.p[8]=WnjL+9216; wp.p[9]=WnsL+9216; wp.p[10]=WfijL+9216;
  wp.p[11]=Wfij0;
  k_prep<<<(WT_ELEMS+255)/256, 256, 0, stream>>>(wp, Wt);

  // ---- CSR by dst (perm = csr_e)
  hipMemsetAsync(counts, 0, (size_t)N_NODES*4, stream);
  hipMemsetAsync(cursor, 0, (size_t)N_NODES*4, stream);
  k_count<<<(N_EDGES+255)/256, 256, 0, stream>>>(dst, counts);
  k_scan<<<1, 1024, 0, stream>>>(counts, row_ptr);
  k_fill<<<(N_EDGES+255)/256, 256, 0, stream>>>(dst, row_ptr, cursor, csr_e);

  dim3 ngrid((N_NODES + 63)/64, F/16, 3);
  int  egrid = N_EDGES/64;
  int  agrid = (N_NODES + 3)/4;

  const bf16 *WtNI0 = Wt,          *WtNJ0 = Wt+9216,   *WtNS0 = Wt+18432;
  const bf16 *WtNI1 = Wt+3*9216,   *WtNJ1 = Wt+4*9216, *WtNS1 = Wt+5*9216, *WtE1 = Wt+6*9216;
  const bf16 *WtNI2 = Wt+7*9216,   *WtNJ2 = Wt+8*9216, *WtNS2 = Wt+9*9216, *WtE2 = Wt+10*9216;
  const bf16 *WtE0  = Wt+11*9216;

  // ---- layer 0
  k_node_gemm<F32S><<<ngrid, 256, 0, stream>>>(ndata, WtNI0, WtNJ0, WtNS0, NI, NJ, HS);
  k_edge7<K_ODF, true, F32S, EFS><<<egrid, 256, 0, stream>>>(
      odfeat, WtE0, NI, NJ, bias0, attn0, src, dst, csr_e, ef, logits);
  k_agg4<true><<<agrid, 256, 0, stream>>>(logits, HS, src, row_ptr, csr_e, nf);

  // ---- layer 1 (ef updated in place, sorted layout)
  k_node_gemm<BF16S><<<ngrid, 256, 0, stream>>>(nf, WtNI1, WtNJ1, WtNS1, NI, NJ, HS);
  k_edge7<F, true, EFS, EFS><<<egrid, 256, 0, stream>>>(
      ef, WtE1, NI, NJ, biasL, attnL, src, dst, csr_e, ef, logits);
  k_agg4<true><<<agrid, 256, 0, stream>>>(logits, HS, src, row_ptr, csr_e, nf);

  // ---- layer 2 (no relu on nh, ef not stored)
  k_node_gemm<BF16S><<<ngrid, 256, 0, stream>>>(nf, WtNI2, WtNJ2, WtNS2, NI, NJ, HS);
  k_edge7<F, false, EFS, EFS><<<egrid, 256, 0, stream>>>(
      ef, WtE2, NI, NJ, biasL+F, attnL+F, src, dst, csr_e, (typename EFS::T*)nullptr, logits);
  k_agg4<false><<<agrid, 256, 0, stream>>>(logits, HS, src, row_ptr, csr_e, nf);

  // ---- output gather
  k_gather<<<(NSEL*F + 255)/256, 256, 0, stream>>>(nf, idxs, out);
}

extern "C" void kernel_launch(void* const* d_in, const int* in_sizes, int n_in,
                              void* d_out, int out_size, void* d_ws, size_t ws_size,
                              hipStream_t stream)
{
  (void)in_sizes; (void)n_in; (void)out_size;
  const float* ndata  = (const float*)d_in[0];
  const float* odfeat = (const float*)d_in[1];
  const int*   src    = (const int*)d_in[2];
  const int*   dst    = (const int*)d_in[3];
  const int*   idxs   = (const int*)d_in[4];
  const float* Wns0   = (const float*)d_in[5];
  const float* Wni0   = (const float*)d_in[6];
  const float* Wfij0  = (const float*)d_in[7];
  const float* Wnj0   = (const float*)d_in[8];
  const float* attn0  = (const float*)d_in[9];
  const float* bias0  = (const float*)d_in[10];
  const float* WnsL   = (const float*)d_in[11];
  const float* WniL   = (const float*)d_in[12];
  const float* WfijL  = (const float*)d_in[13];
  const float* WnjL   = (const float*)d_in[14];
  const float* attnL  = (const float*)d_in[15];
  const float* biasL  = (const float*)d_in[16];

  // bf16-ef plan needs ~205.7 MB of ws; fp8-ef plan needs ~129 MB.
  bool planA = ws_size >= (size_t)206000000;
  if (planA)
    run_all<BF16S>(ndata, odfeat, src, dst, idxs, Wns0, Wni0, Wfij0, Wnj0, attn0, bias0,
                   WnsL, WniL, WfijL, WnjL, attnL, biasL,
                   (float*)d_out, (char*)d_ws, stream);
  else
    run_all<FP8S>(ndata, odfeat, src, dst, idxs, Wns0, Wni0, Wfij0, Wnj0, attn0, bias0,
                  WnsL, WniL, WfijL, WnjL, attnL, biasL,
                  (float*)d_out, (char*)d_ws, stream);
}

// Round 11
// 828.242 us; speedup vs baseline: 1.3396x; 1.0280x over previous
//
#include <hip/hip_runtime.h>
#include <hip/hip_bf16.h>
#include <cstdint>
#include <cstddef>

#define N_NODES 50000
#define N_EDGES 800000
#define NSEL    4096
#define F       96     // H*HN == H*HE
#define K_ODF   16

typedef __attribute__((ext_vector_type(8))) short  short8;
typedef __attribute__((ext_vector_type(4))) float  floatx4;
typedef __attribute__((ext_vector_type(4))) int    intx4;
typedef __attribute__((ext_vector_type(4))) unsigned int uintx4;

using bf16 = __hip_bfloat16;

__device__ inline float b2f(bf16 x){ return __bfloat162float(x); }
__device__ inline bf16  f2b(float x){ return __float2bfloat16(x); }
__device__ inline short f2bs(float x){ return __builtin_bit_cast(short, __float2bfloat16(x)); }
__device__ inline int clampi(int v, int hi){ return v < 0 ? 0 : (v >= hi ? hi-1 : v); }

// packed bf16 add: (a.lo+b.lo, a.hi+b.hi) with RNE via f32
__device__ inline unsigned int addpk_bf16(unsigned int a, unsigned int b){
  float alo = __builtin_bit_cast(float, a<<16);
  float ahi = __builtin_bit_cast(float, a & 0xffff0000u);
  float blo = __builtin_bit_cast(float, b<<16);
  float bhi = __builtin_bit_cast(float, b & 0xffff0000u);
  unsigned int pl = (unsigned int)(unsigned short)f2bs(alo+blo);
  unsigned int ph = (unsigned int)(unsigned short)f2bs(ahi+bhi);
  return pl | (ph<<16);
}

// ---------------- storage policies ----------------
struct F32S {
  using T = float;
  static constexpr size_t bytes = 4;
  static __device__ short8 ld8(const T* p){
    float4 u = *(const float4*)p;
    float4 v = *(const float4*)(p+4);
    short8 r;
    r[0]=f2bs(u.x); r[1]=f2bs(u.y); r[2]=f2bs(u.z); r[3]=f2bs(u.w);
    r[4]=f2bs(v.x); r[5]=f2bs(v.y); r[6]=f2bs(v.z); r[7]=f2bs(v.w);
    return r;
  }
  static __device__ short8 lds_ld(const char*){ return short8{0,0,0,0,0,0,0,0}; }
  static __device__ void lds_st(char*, float){}
};
struct BF16S {
  using T = bf16;
  static constexpr size_t bytes = 2;
  static __device__ short8 ld8(const T* p){ return *(const short8*)p; }
  static __device__ short8 lds_ld(const char* p){ return *(const short8*)p; }
  static __device__ void lds_st(char* p, float v){ *(bf16*)p = f2b(v); }
};
struct FP8S {
  using T = unsigned char;
  static constexpr size_t bytes = 1;
  static __device__ short8 cvt8(int2 w){
    short8 r;
    r[0]=f2bs(__builtin_amdgcn_cvt_f32_fp8(w.x,0));
    r[1]=f2bs(__builtin_amdgcn_cvt_f32_fp8(w.x,1));
    r[2]=f2bs(__builtin_amdgcn_cvt_f32_fp8(w.x,2));
    r[3]=f2bs(__builtin_amdgcn_cvt_f32_fp8(w.x,3));
    r[4]=f2bs(__builtin_amdgcn_cvt_f32_fp8(w.y,0));
    r[5]=f2bs(__builtin_amdgcn_cvt_f32_fp8(w.y,1));
    r[6]=f2bs(__builtin_amdgcn_cvt_f32_fp8(w.y,2));
    r[7]=f2bs(__builtin_amdgcn_cvt_f32_fp8(w.y,3));
    return r;
  }
  static __device__ short8 ld8(const T* p){ return cvt8(*(const int2*)p); }
  static __device__ short8 lds_ld(const char* p){ return cvt8(*(const int2*)p); }
  static __device__ void lds_st(char* p, float v){
    int pk = __builtin_amdgcn_cvt_pk_fp8_f32(v, 0.f, 0, false);
    *(unsigned char*)p = (unsigned char)(pk & 0xff);
  }
};

// ---------------- weight prep: bf16 transposed Wt[c][k] ----------------
struct WP { const float* p[12]; };
#define WT_ELEMS (11*9216 + 1536)

__global__ void k_prep(WP w, bf16* __restrict__ Wt){
  int g = blockIdx.x*blockDim.x + threadIdx.x;
  if (g >= WT_ELEMS) return;
  float v;
  if (g < 11*9216){
    int id = g / 9216, s = g % 9216;
    int c = s / 96, k = s % 96;
    v = w.p[id][k*96 + c];
  } else {
    int s = g - 11*9216;
    int c = s / 16, k = s % 16;
    v = w.p[11][k*96 + c];
  }
  Wt[g] = f2b(v);
}

// ---------------- CSR build ----------------
__global__ void k_count(const int* __restrict__ dst, int* __restrict__ counts){
  int e = blockIdx.x*blockDim.x + threadIdx.x;
  if (e < N_EDGES) atomicAdd(&counts[clampi(dst[e], N_NODES)], 1);
}

__global__ void k_scan(const int* __restrict__ counts, int* __restrict__ row_ptr){
  const int T = 1024;
  const int n = N_NODES;
  int tid = threadIdx.x;
  int seg = (n + T - 1)/T;
  int start = tid*seg;
  int end = (start+seg < n) ? start+seg : n;
  int s = 0;
  for (int i=start;i<end;i++) s += counts[i];
  __shared__ int wsums[16];
  int lane = tid & 63, wid = tid >> 6;
  int v = s;
  #pragma unroll
  for (int off=1; off<64; off<<=1){
    int t = __shfl_up(v, off);
    if (lane >= off) v += t;
  }
  if (lane==63) wsums[wid] = v;
  __syncthreads();
  if (wid==0 && lane < 16){
    int w = wsums[lane];
    #pragma unroll
    for (int off=1; off<16; off<<=1){
      int t = __shfl_up(w, off);
      if (lane>=off) w += t;
    }
    wsums[lane] = w;
  }
  __syncthreads();
  int base = (wid>0 ? wsums[wid-1] : 0) + (v - s);
  int run = base;
  for (int i=start;i<end;i++){ row_ptr[i] = run; run += counts[i]; }
  if (tid==T-1) row_ptr[n] = run;
}

// fill perm; optionally also sd[i] = (src,dst) at sorted position i
__global__ void k_fill(const int* __restrict__ src, const int* __restrict__ dst,
                       const int* __restrict__ row_ptr,
                       int* __restrict__ cursor, int* __restrict__ csr_e,
                       int2* __restrict__ sd){
  int e = blockIdx.x*blockDim.x + threadIdx.x;
  if (e < N_EDGES){
    int t = clampi(dst[e], N_NODES);
    int pos = atomicAdd(&cursor[t], 1);
    int idx = row_ptr[t] + pos;
    if (idx >= 0 && idx < N_EDGES){
      csr_e[idx] = e;
      if (sd) sd[idx] = make_int2(src[e], dst[e]);
    }
  }
}

// ---------------- node GEMM: O = A @ W  (W from transposed bf16 Wt) ----------------
template<class AS>
__global__ __launch_bounds__(256) void k_node_gemm(
    const typename AS::T* A,
    const bf16* __restrict__ Wt_ni, const bf16* __restrict__ Wt_nj, const bf16* __restrict__ Wt_ns,
    bf16* __restrict__ NI, bf16* __restrict__ NJ, bf16* __restrict__ HS)
{
  const bf16* Wt; bf16* O;
  if (blockIdx.z==0){ Wt=Wt_ni; O=NI; } else if (blockIdx.z==1){ Wt=Wt_nj; O=NJ; } else { Wt=Wt_ns; O=HS; }
  int wave = threadIdx.x >> 6, lane = threadIdx.x & 63;
  int lo = lane & 15, q = lane >> 4;
  int m0 = (blockIdx.x*4 + wave)*16;
  int n0 = blockIdx.y*16;
  int row = m0 + lo; if (row >= N_NODES) row = N_NODES-1;
  floatx4 acc = {0.f,0.f,0.f,0.f};
  #pragma unroll
  for (int kb=0; kb<3; kb++){
    int k0 = kb*32 + q*8;
    short8 a = AS::ld8(A + (size_t)row*F + k0);
    short8 b = *(const short8*)(Wt + (size_t)(n0+lo)*96 + k0);
    acc = __builtin_amdgcn_mfma_f32_16x16x32_bf16(a,b,acc,0,0,0);
  }
  #pragma unroll
  for (int r=0;r<4;r++){
    int m = m0 + q*4 + r;
    if (m < N_NODES) O[(size_t)m*F + n0+lo] = f2b(acc[r]);
  }
}

// ---------------- fused edge kernel v8: sorted positions, single LDS buffer,
// optional sd (src,dst per position), non-temporal ef/logits streaming ----------------
template<int K_IN, bool STORE_EF, class INS, class OUTS>
__global__ __launch_bounds__(256) void k_edge8(
    const typename INS::T* EF, const bf16* __restrict__ Wt,
    const bf16* __restrict__ NI, const bf16* __restrict__ NJ,
    const float* __restrict__ bias, const float* __restrict__ attn,
    const int* __restrict__ src, const int* __restrict__ dst,
    const int* __restrict__ perm, const int2* __restrict__ sd,
    typename OUTS::T* EFO, float* __restrict__ logits)
{
  constexpr bool ONEBUF = ((int)OUTS::bytes == 2) || !STORE_EF;
  __shared__ __align__(16) char lds_a[4][3328];
  __shared__ __align__(16) char lds_b[4][ONEBUF ? 16 : 3328];
  __shared__ __align__(16) float lstage[4][48];

  int wave = threadIdx.x >> 6, lane = threadIdx.x & 63;
  int lo = lane & 15, q = lane >> 4;
  size_t p0 = ((size_t)blockIdx.x*4 + wave)*16;
  char* myl = lds_a[wave];
  char* gl  = ONEBUF ? myl : lds_b[wave];

  // per-lane (row) src/dst indices for G staging — one contiguous hop if sd given
  int seL[3], deL[3];
  if (sd){
    #pragma unroll
    for (int j=0;j<3;j++){
      int2 v = sd[p0 + (j*64+lane)/12];
      seL[j] = clampi(v.x, N_NODES); deL[j] = clampi(v.y, N_NODES);
    }
  } else {
    int eL[3];
    #pragma unroll
    for (int j=0;j<3;j++) eL[j] = perm[p0 + (j*64+lane)/12];
    #pragma unroll
    for (int j=0;j<3;j++){ seL[j] = clampi(src[eL[j]], N_NODES); deL[j] = clampi(dst[eL[j]], N_NODES); }
  }

  // ---- stage ef + load A-fragments FIRST (buffer freed for G afterwards)
  short8 afr[(K_IN+31)/32];
  if constexpr (K_IN == 96){
    constexpr int RS  = 96*(int)INS::bytes + 16;
    constexpr int CPR = (96*(int)INS::bytes)/16;
    #pragma unroll
    for (int j=0; j*64 < 16*CPR; j++){
      int chunk = j*64 + lane;
      if ((16*CPR) % 64 == 0 || chunk < 16*CPR){
        int er = chunk / CPR, c16 = chunk % CPR;
        intx4 v = __builtin_nontemporal_load(
            (const intx4*)((const char*)EF + ((p0+er)*96)*INS::bytes + (size_t)c16*16));
        *(intx4*)(myl + er*RS + c16*16) = v;
      }
    }
    #pragma unroll
    for (int kb=0; kb<3; kb++)
      afr[kb] = INS::lds_ld(myl + lo*RS + (kb*32 + q*8)*(int)INS::bytes);
  } else {
    int pe = perm[p0 + lo];
    if (q < 2) afr[0] = INS::ld8(EF + (size_t)pe*K_IN + q*8);
    else       afr[0] = short8{0,0,0,0,0,0,0,0};
  }

  // ---- stage G = NI[src]+NJ[dst] (bf16, stride 208) into gl (may alias myl)
  #pragma unroll
  for (int j=0;j<3;j++){
    int chunk = j*64 + lane;
    int er = chunk/12, c16 = chunk - er*12;
    uintx4 a = *(const uintx4*)((const char*)NI + (size_t)seL[j]*192 + c16*16);
    uintx4 b = *(const uintx4*)((const char*)NJ + (size_t)deL[j]*192 + c16*16);
    uintx4 g;
    g.x = addpk_bf16(a.x,b.x); g.y = addpk_bf16(a.y,b.y);
    g.z = addpk_bf16(a.z,b.z); g.w = addpk_bf16(a.w,b.w);
    *(uintx4*)(gl + er*208 + c16*16) = g;
  }

  float hsum[3][4] = {{0.f,0.f,0.f,0.f},{0.f,0.f,0.f,0.f},{0.f,0.f,0.f,0.f}};
  constexpr int ORS = 96*(int)OUTS::bytes + 16;   // == 208 for bf16 (same as G stride)

  #pragma unroll
  for (int t=0; t<6; t++){
    int col = t*16 + lo;
    floatx4 acc = {0.f,0.f,0.f,0.f};
    if constexpr (K_IN == 96){
      #pragma unroll
      for (int kb=0; kb<3; kb++){
        short8 b = *(const short8*)(Wt + (size_t)col*96 + kb*32 + q*8);
        acc = __builtin_amdgcn_mfma_f32_16x16x32_bf16(afr[kb], b, acc, 0,0,0);
      }
    } else {
      short8 b = (q<2) ? *(const short8*)(Wt + (size_t)col*16 + q*8)
                       : short8{0,0,0,0,0,0,0,0};
      acc = __builtin_amdgcn_mfma_f32_16x16x32_bf16(afr[0], b, acc, 0,0,0);
    }
    float aw = attn[col];
    float bv = bias[col];
    #pragma unroll
    for (int r=0;r<4;r++){
      char* gslot = gl + (q*4+r)*208 + col*2;
      float gv = b2f(*(const bf16*)gslot);
      float pre = acc[r] + gv + bv;
      if constexpr (STORE_EF){
        if constexpr (ONEBUF) *(bf16*)gslot = f2b(fmaxf(pre, 0.f));   // out overwrites dead G slot
        else OUTS::lds_st(myl + (q*4+r)*ORS + col*(int)OUTS::bytes, fmaxf(pre, 0.f));
      }
      float lk = pre > 0.f ? pre : 0.01f*pre;
      hsum[t>>1][r] += lk*aw;
    }
  }

  // reduce logits within each 16-lane group, stage, store as dwordx4 (linear)
  #pragma unroll
  for (int h=0;h<3;h++){
    #pragma unroll
    for (int r=0;r<4;r++){
      float v = hsum[h][r];
      v += __shfl_xor(v,1);
      v += __shfl_xor(v,2);
      v += __shfl_xor(v,4);
      v += __shfl_xor(v,8);
      if (lo==0) lstage[wave][(q*4+r)*3 + h] = v;
    }
  }
  if (lane < 12){
    floatx4 v = *(const floatx4*)(&lstage[wave][lane*4]);
    __builtin_nontemporal_store(v, (floatx4*)((char*)logits + p0*12 + (size_t)lane*16));
  }

  if constexpr (STORE_EF){
    const char* ob = ONEBUF ? gl : myl;
    constexpr int OCPR = (96*(int)OUTS::bytes)/16;
    #pragma unroll
    for (int j=0; j*64 < 16*OCPR; j++){
      int chunk = j*64 + lane;
      if ((16*OCPR) % 64 == 0 || chunk < 16*OCPR){
        int er = chunk / OCPR, c16 = chunk % OCPR;
        intx4 v = *(const intx4*)(ob + er*ORS + c16*16);
        __builtin_nontemporal_store(v,
            (intx4*)((char*)EFO + ((p0+er)*96)*OUTS::bytes + (size_t)c16*16));
      }
    }
  }
}

// ---------------- softmax+aggregate: ONE WAVE PER NODE, contiguous logits ----------------
template<bool RELU>
__global__ __launch_bounds__(256) void k_agg5(
    const float* __restrict__ logits,
    const bf16* __restrict__ HS,
    const int* __restrict__ src,
    const int* __restrict__ row_ptr, const int* __restrict__ perm,
    const int2* __restrict__ sd,
    bf16* nf_out)
{
  int wave = threadIdx.x >> 6, lane = threadIdx.x & 63;
  int node = blockIdx.x*4 + wave;
  if (node >= N_NODES) return;
  int r0 = row_ptr[node], r1 = row_ptr[node+1];

  float m0=-3.0e38f, m1=-3.0e38f, m2=-3.0e38f;
  for (int i = r0 + lane; i < r1; i += 64){
    const float* lp = logits + (size_t)i*3;
    m0 = fmaxf(m0, lp[0]);
    m1 = fmaxf(m1, lp[1]);
    m2 = fmaxf(m2, lp[2]);
  }
  #pragma unroll
  for (int o=1;o<64;o<<=1){
    m0 = fmaxf(m0, __shfl_xor(m0,o));
    m1 = fmaxf(m1, __shfl_xor(m1,o));
    m2 = fmaxf(m2, __shfl_xor(m2,o));
  }

  if (lane >= 48) return;
  float ox = 0.f, oy = 0.f;
  if (r1 > r0){
    int h = (2*lane) >> 5;
    float mm = (h==0) ? m0 : (h==1 ? m1 : m2);
    float ax = 0.f, ay = 0.f, ss = 0.f;
    if (sd){
      #pragma unroll 4
      for (int i = r0; i < r1; i++){
        float al = __expf(logits[(size_t)i*3 + h] - mm);
        int s = clampi(sd[i].x, N_NODES);
        unsigned w = *(const unsigned*)((const char*)HS + (size_t)s*192 + lane*4);
        float x = __builtin_bit_cast(float, w << 16);
        float y = __builtin_bit_cast(float, w & 0xffff0000u);
        ax += al*x; ay += al*y; ss += al;
      }
    } else {
      #pragma unroll 4
      for (int i = r0; i < r1; i++){
        float al = __expf(logits[(size_t)i*3 + h] - mm);
        int e = perm[i];
        unsigned w = *(const unsigned*)((const char*)HS + (size_t)clampi(src[e],N_NODES)*192 + lane*4);
        float x = __builtin_bit_cast(float, w << 16);
        float y = __builtin_bit_cast(float, w & 0xffff0000u);
        ax += al*x; ay += al*y; ss += al;
      }
    }
    float invs = 1.0f/ss;
    ox = ax*invs; oy = ay*invs;
    if (RELU){ ox = fmaxf(ox,0.f); oy = fmaxf(oy,0.f); }
  }
  unsigned lo16 = (unsigned)(unsigned short)f2bs(ox);
  unsigned hi16 = (unsigned)(unsigned short)f2bs(oy);
  *(unsigned*)((char*)nf_out + (size_t)node*192 + lane*4) = lo16 | (hi16<<16);
}

// ---------------- output gather (f32 out) ----------------
__global__ void k_gather(const bf16* __restrict__ nf, const int* __restrict__ idxs,
                         float* __restrict__ out){
  int t = blockIdx.x*blockDim.x + threadIdx.x;
  if (t < NSEL*F){
    int i = t / F, c = t % F;
    out[t] = b2f(nf[(size_t)clampi(idxs[i], N_NODES)*F + c]);
  }
}

// ---------------- driver ----------------
template<class EFS>
static void run_all(const float* ndata, const float* odfeat, const int* src, const int* dst,
                    const int* idxs,
                    const float* Wns0, const float* Wni0, const float* Wfij0, const float* Wnj0,
                    const float* attn0, const float* bias0,
                    const float* WnsL, const float* WniL, const float* WfijL, const float* WnjL,
                    const float* attnL, const float* biasL,
                    float* out, char* ws, size_t ws_size, hipStream_t stream)
{
  size_t off = 0;
  auto alloc = [&](size_t bytes)->char*{
    char* p = ws + off; off += (bytes + 255) & ~(size_t)255; return p;
  };
  typename EFS::T* ef = (typename EFS::T*)alloc((size_t)N_EDGES*F*EFS::bytes);
  bf16* NI      = (bf16*)alloc((size_t)N_NODES*F*2);
  bf16* NJ      = (bf16*)alloc((size_t)N_NODES*F*2);
  bf16* HS      = (bf16*)alloc((size_t)N_NODES*F*2);
  bf16* nf      = (bf16*)alloc((size_t)N_NODES*F*2);
  float* logits = (float*)alloc((size_t)N_EDGES*3*4);
  int*  row_ptr = (int*)alloc((size_t)(N_NODES+1)*4);
  int*  counts  = (int*)alloc((size_t)N_NODES*4);
  int*  cursor  = (int*)alloc((size_t)N_NODES*4);
  int*  csr_e   = (int*)alloc((size_t)N_EDGES*4);
  bf16* Wt      = (bf16*)alloc((size_t)WT_ELEMS*2);
  // optional sd (src,dst per sorted position): only if ws has room beyond the known-good layout
  int2* sd = nullptr;
  if (ws_size >= off + (size_t)N_EDGES*8 + 1024)
    sd = (int2*)alloc((size_t)N_EDGES*8);

  // ---- weight prep (bf16, transposed [c][k])
  WP wp;
  wp.p[0]=Wni0; wp.p[1]=Wnj0; wp.p[2]=Wns0;
  wp.p[3]=WniL; wp.p[4]=WnjL; wp.p[5]=WnsL; wp.p[6]=WfijL;
  wp.p[7]=WniL+9216; wp.p[8]=WnjL+9216; wp.p[9]=WnsL+9216; wp.p[10]=WfijL+9216;
  wp.p[11]=Wfij0;
  k_prep<<<(WT_ELEMS+255)/256, 256, 0, stream>>>(wp, Wt);

  // ---- CSR by dst (perm = csr_e, plus optional sd)
  hipMemsetAsync(counts, 0, (size_t)N_NODES*4, stream);
  hipMemsetAsync(cursor, 0, (size_t)N_NODES*4, stream);
  k_count<<<(N_EDGES+255)/256, 256, 0, stream>>>(dst, counts);
  k_scan<<<1, 1024, 0, stream>>>(counts, row_ptr);
  k_fill<<<(N_EDGES+255)/256, 256, 0, stream>>>(src, dst, row_ptr, cursor, csr_e, sd);

  dim3 ngrid((N_NODES + 63)/64, F/16, 3);
  int  egrid = N_EDGES/64;
  int  agrid = (N_NODES + 3)/4;

  const bf16 *WtNI0 = Wt,          *WtNJ0 = Wt+9216,   *WtNS0 = Wt+18432;
  const bf16 *WtNI1 = Wt+3*9216,   *WtNJ1 = Wt+4*9216, *WtNS1 = Wt+5*9216, *WtE1 = Wt+6*9216;
  const bf16 *WtNI2 = Wt+7*9216,   *WtNJ2 = Wt+8*9216, *WtNS2 = Wt+9*9216, *WtE2 = Wt+10*9216;
  const bf16 *WtE0  = Wt+11*9216;

  // ---- layer 0
  k_node_gemm<F32S><<<ngrid, 256, 0, stream>>>(ndata, WtNI0, WtNJ0, WtNS0, NI, NJ, HS);
  k_edge8<K_ODF, true, F32S, EFS><<<egrid, 256, 0, stream>>>(
      odfeat, WtE0, NI, NJ, bias0, attn0, src, dst, csr_e, sd, ef, logits);
  k_agg5<true><<<agrid, 256, 0, stream>>>(logits, HS, src, row_ptr, csr_e, sd, nf);

  // ---- layer 1 (ef updated in place, sorted layout)
  k_node_gemm<BF16S><<<ngrid, 256, 0, stream>>>(nf, WtNI1, WtNJ1, WtNS1, NI, NJ, HS);
  k_edge8<F, true, EFS, EFS><<<egrid, 256, 0, stream>>>(
      ef, WtE1, NI, NJ, biasL, attnL, src, dst, csr_e, sd, ef, logits);
  k_agg5<true><<<agrid, 256, 0, stream>>>(logits, HS, src, row_ptr, csr_e, sd, nf);

  // ---- layer 2 (no relu on nh, ef not stored)
  k_node_gemm<BF16S><<<ngrid, 256, 0, stream>>>(nf, WtNI2, WtNJ2, WtNS2, NI, NJ, HS);
  k_edge8<F, false, EFS, EFS><<<egrid, 256, 0, stream>>>(
      ef, WtE2, NI, NJ, biasL+F, attnL+F, src, dst, csr_e, sd, (typename EFS::T*)nullptr, logits);
  k_agg5<false><<<agrid, 256, 0, stream>>>(logits, HS, src, row_ptr, csr_e, sd, nf);

  // ---- output gather
  k_gather<<<(NSEL*F + 255)/256, 256, 0, stream>>>(nf, idxs, out);
}

extern "C" void kernel_launch(void* const* d_in, const int* in_sizes, int n_in,
                              void* d_out, int out_size, void* d_ws, size_t ws_size,
                              hipStream_t stream)
{
  (void)in_sizes; (void)n_in; (void)out_size;
  const float* ndata  = (const float*)d_in[0];
  const float* odfeat = (const float*)d_in[1];
  const int*   src    = (const int*)d_in[2];
  const int*   dst    = (const int*)d_in[3];
  const int*   idxs   = (const int*)d_in[4];
  const float* Wns0   = (const float*)d_in[5];
  const float* Wni0   = (const float*)d_in[6];
  const float* Wfij0  = (const float*)d_in[7];
  const float* Wnj0   = (const float*)d_in[8];
  const float* attn0  = (const float*)d_in[9];
  const float* bias0  = (const float*)d_in[10];
  const float* WnsL   = (const float*)d_in[11];
  const float* WniL   = (const float*)d_in[12];
  const float* WfijL  = (const float*)d_in[13];
  const float* WnjL   = (const float*)d_in[14];
  const float* attnL  = (const float*)d_in[15];
  const float* biasL  = (const float*)d_in[16];

  // bf16-ef plan needs ~205.7 MB of ws (sd adds 6.4 MB, used only if present);
  // fp8-ef plan needs ~129 MB.
  bool planA = ws_size >= (size_t)206000000;
  if (planA)
    run_all<BF16S>(ndata, odfeat, src, dst, idxs, Wns0, Wni0, Wfij0, Wnj0, attn0, bias0,
                   WnsL, WniL, WfijL, WnjL, attnL, biasL,
                   (float*)d_out, (char*)d_ws, ws_size, stream);
  else
    run_all<FP8S>(ndata, odfeat, src, dst, idxs, Wns0, Wni0, Wfij0, Wnj0, attn0, bias0,
                  WnsL, WniL, WfijL, WnjL, attnL, biasL,
                  (float*)d_out, (char*)d_ws, ws_size, stream);
}